// Round 2
// baseline (1215.851 us; speedup 1.0000x reference)
//
#include <hip/hip_runtime.h>

#define M_REAL   54000
#define N_TOT    60000
#define N_EDGE   1000000
#define MAXDEG   64

// ---------------------------------------------------------------------------
// Build bucketed CSR (strided layout, no scan needed) + ghost row remap.
// bucketS[p * M_REAL + c] = edge id of the p-th edge whose col == c.
// row_remap[e] = row[e] < M ? row[e] : ghostIndices[row[e]]  (for layers 1,2)
// ---------------------------------------------------------------------------
__global__ void build_kernel(const int* __restrict__ row,
                             const int* __restrict__ col,
                             const int* __restrict__ ghost,
                             int* __restrict__ counts,
                             int* __restrict__ bucketS,
                             int* __restrict__ row_remap) {
    int e = blockIdx.x * blockDim.x + threadIdx.x;
    if (e >= N_EDGE) return;
    int c = col[e];
    int p = atomicAdd(&counts[c], 1);
    if (p < MAXDEG) bucketS[p * M_REAL + c] = e;
    int r = row[e];
    row_remap[e] = (r < M_REAL) ? r : ghost[r];
}

// ---------------------------------------------------------------------------
// Fused conv layer: per-dst T accumulation (registers) + einsum with W (LDS).
// Block = 256 threads = 8 half-waves; each half-wave owns one dst per
// iteration. Lane = input feature k in edge phase, output feature l in einsum.
// IMPORTANT: basis is computed from the RAW row position (rowpos) — ghost
// rows have their own positions; only the FEATURE gather uses the remapped
// row (rowfeat).
// ---------------------------------------------------------------------------
__global__ __launch_bounds__(256) void conv_kernel(
        const float* __restrict__ xin,       // [*,32] input features
        const int*   __restrict__ rowpos,    // per-edge RAW source row (positions)
        const int*   __restrict__ rowfeat,   // per-edge source row for features
        const float* __restrict__ positions, // [N_TOT,2]
        const float* __restrict__ outpos,    // [M,2]
        const float* __restrict__ supportp,  // [1]
        const int*   __restrict__ counts,    // [M]
        const int*   __restrict__ bucketS,   // [MAXDEG*M]
        const float* __restrict__ W,         // [9,32,32] (b,k,l)
        float*       __restrict__ yout,      // [M,32]
        int act) {
    __shared__ float Wlds[9 * 32 * 32];        // 36 KB
    __shared__ float t_lds[8 * 32 * 12];       // 12 KB (pad 9 -> 12)

    const int tid  = threadIdx.x;
    const int lane = tid & 31;
    const int slot = tid >> 5;

    for (int i = tid; i < 9 * 32 * 32; i += 256) Wlds[i] = W[i];
    const float invs = 1.0f / supportp[0];
    __syncthreads();

    const int dbase = blockIdx.x * 64;
    for (int it = 0; it < 8; ++it) {
        const int m = dbase + it * 8 + slot;
        const bool valid = (m < M_REAL);

        float t[9];
#pragma unroll
        for (int b = 0; b < 9; ++b) t[b] = 0.0f;

        if (valid) {
            int deg = counts[m];
            if (deg > MAXDEG) deg = MAXDEG;
            const float ox = outpos[2 * m];
            const float oy = outpos[2 * m + 1];
            for (int i = 0; i < deg; ++i) {
                const int e  = bucketS[i * M_REAL + m];
                const int rp = rowpos[e];    // raw row: position source
                const int rf = rowfeat[e];   // remapped row: feature source
                const float px = positions[2 * rp];
                const float py = positions[2 * rp + 1];
                float du = (ox - px) * invs;
                float dv = (oy - py) * invs;
                du = fminf(fmaxf(du, -1.0f), 1.0f);
                dv = fminf(fmaxf(dv, -1.0f), 1.0f);
                const float a0 = du + 1.0f, a2 = du - 1.0f;
                const float c0 = dv + 1.0f, c2 = dv - 1.0f;
                const float u0 = __expf(-a0 * a0);
                const float u1 = __expf(-du * du);
                const float u2 = __expf(-a2 * a2);
                const float v0 = __expf(-c0 * c0);
                const float v1 = __expf(-dv * dv);
                const float v2 = __expf(-c2 * c2);
                const float x = xin[rf * 32 + lane];
                t[0] += (u0 * v0) * x;
                t[1] += (u0 * v1) * x;
                t[2] += (u0 * v2) * x;
                t[3] += (u1 * v0) * x;
                t[4] += (u1 * v1) * x;
                t[5] += (u1 * v2) * x;
                t[6] += (u2 * v0) * x;
                t[7] += (u2 * v1) * x;
                t[8] += (u2 * v2) * x;
            }
        }

        // exchange t across lanes: t_lds[slot][k][b]
        {
            float* tl = &t_lds[(slot * 32 + lane) * 12];
#pragma unroll
            for (int b = 0; b < 9; ++b) tl[b] = t[b];
        }
        __syncthreads();

        if (valid) {
            float acc = 0.0f;
            const float* tb = &t_lds[slot * 32 * 12];
#pragma unroll 4
            for (int k = 0; k < 32; ++k) {
                const float* tk = &tb[k * 12];
#pragma unroll
                for (int b = 0; b < 9; ++b)
                    acc += tk[b] * Wlds[b * 1024 + k * 32 + lane];
            }
            if (act) acc = fmaxf(acc, 0.0f);
            yout[m * 32 + lane] = acc;
        }
        __syncthreads();
    }
}

// ---------------------------------------------------------------------------
// Fill ghost rows of the final output: out[M+i] = out[ghost[M+i]]
// ---------------------------------------------------------------------------
__global__ void ghost_kernel(const int* __restrict__ ghost,
                             float* __restrict__ out) {
    int idx = blockIdx.x * blockDim.x + threadIdx.x;
    if (idx >= (N_TOT - M_REAL) * 32) return;
    int i = idx >> 5;
    int k = idx & 31;
    int g = ghost[M_REAL + i];
    out[(M_REAL + i) * 32 + k] = out[g * 32 + k];
}

extern "C" void kernel_launch(void* const* d_in, const int* in_sizes, int n_in,
                              void* d_out, int out_size, void* d_ws, size_t ws_size,
                              hipStream_t stream) {
    const float* positions = (const float*)d_in[0];
    const float* features  = (const float*)d_in[1];
    const float* outpos    = (const float*)d_in[2];
    const int*   ghost     = (const int*)d_in[3];
    const float* support   = (const float*)d_in[4];
    const int*   edge      = (const int*)d_in[5];   // [2,E] row-major
    const float* W0        = (const float*)d_in[6];
    const float* W1        = (const float*)d_in[7];
    const float* W2        = (const float*)d_in[8];
    float* out = (float*)d_out;

    char* ws = (char*)d_ws;
    int* counts    = (int*)ws;  ws += ((size_t)M_REAL * 4 + 255) / 256 * 256;
    int* bucketS   = (int*)ws;  ws += (size_t)MAXDEG * M_REAL * 4;
    int* row_remap = (int*)ws;  ws += (size_t)N_EDGE * 4;
    float* out0    = (float*)ws; ws += (size_t)M_REAL * 32 * 4;
    float* out1    = (float*)ws;

    const int* erow = edge;
    const int* ecol = edge + N_EDGE;

    hipMemsetAsync(counts, 0, (size_t)M_REAL * 4, stream);
    build_kernel<<<(N_EDGE + 255) / 256, 256, 0, stream>>>(
        erow, ecol, ghost, counts, bucketS, row_remap);

    dim3 grid((M_REAL + 63) / 64), block(256);
    // layer 0: input = features (N_TOT rows), raw rows for BOTH pos and feat
    conv_kernel<<<grid, block, 0, stream>>>(features, erow, erow, positions, outpos,
                                            support, counts, bucketS, W0, out0, 1);
    // layer 1: input = out0 (M rows); raw rows for pos, remapped for feat
    conv_kernel<<<grid, block, 0, stream>>>(out0, erow, row_remap, positions, outpos,
                                            support, counts, bucketS, W1, out1, 1);
    // layer 2: input = out1; no act; write real rows of d_out
    conv_kernel<<<grid, block, 0, stream>>>(out1, erow, row_remap, positions, outpos,
                                            support, counts, bucketS, W2, out, 0);
    // fill ghost rows of d_out
    ghost_kernel<<<((N_TOT - M_REAL) * 32 + 255) / 256, 256, 0, stream>>>(ghost, out);
}

// Round 3
// 493.651 us; speedup vs baseline: 2.4630x; 2.4630x over previous
//
#include <hip/hip_runtime.h>
#include <hip/hip_fp16.h>

#define M_REAL   54000
#define N_TOT    60000
#define N_EDGE   1000000

// ---------------------------------------------------------------------------
// Build: one pass over edges. Precomputes everything a conv layer needs per
// edge, packed to 8 bytes, stored in a CONTIGUOUS per-dst bucket:
//   bucketData[c*maxdeg + p] = { raw_row | remap_row<<16 , half2(du,dv) }
// raw_row < 60000 and remap_row < 54000 both fit in u16.
// du/dv are the clipped pseudo-coords (layer-invariant); exps recomputed in
// conv (VALU is idle there).
// ---------------------------------------------------------------------------
__global__ void build_kernel(const int* __restrict__ row,
                             const int* __restrict__ col,
                             const int* __restrict__ ghost,
                             const float* __restrict__ positions,
                             const float* __restrict__ outpos,
                             const float* __restrict__ supportp,
                             int* __restrict__ counts,
                             uint2* __restrict__ bucketData,
                             int maxdeg) {
    int e = blockIdx.x * blockDim.x + threadIdx.x;
    if (e >= N_EDGE) return;
    const int c = col[e];
    const int r = row[e];
    const int rm = (r < M_REAL) ? r : ghost[r];
    const float invs = 1.0f / supportp[0];
    const float du0 = (outpos[2 * c]     - positions[2 * r])     * invs;
    const float dv0 = (outpos[2 * c + 1] - positions[2 * r + 1]) * invs;
    const float du = fminf(fmaxf(du0, -1.0f), 1.0f);
    const float dv = fminf(fmaxf(dv0, -1.0f), 1.0f);
    __half2 h2 = __floats2half2_rn(du, dv);
    uint2 d;
    d.x = (unsigned)r | ((unsigned)rm << 16);
    d.y = *reinterpret_cast<unsigned*>(&h2);
    int p = atomicAdd(&counts[c], 1);
    if (p < maxdeg) bucketData[(size_t)c * maxdeg + p] = d;
}

// ---------------------------------------------------------------------------
// Fused conv layer. Block = 256 = 8 half-waves; half-wave owns one dst per
// iteration (8 its -> 64 dsts/block). Lane = input feat k (edge phase) then
// output feat l (einsum). Edge loop unrolled x4: 2 uint4 broadcast bucket
// loads + 4 independent feature gathers in flight.
// ---------------------------------------------------------------------------
__global__ __launch_bounds__(256) void conv_kernel(
        const float* __restrict__ xin,        // [*,32]
        const int*   __restrict__ counts,     // [M]
        const uint2* __restrict__ bucketData, // [M*maxdeg]
        const float* __restrict__ W,          // [9,32,32] (b,k,l)
        float*       __restrict__ yout,       // [M,32]
        int act, int use_hi, int maxdeg) {
    __shared__ float Wlds[9 * 32 * 32];        // 36 KB
    __shared__ float t_lds[8 * 32 * 12];       // 12 KB (pad 9 -> 12 for float4)

    const int tid  = threadIdx.x;
    const int lane = tid & 31;
    const int slot = tid >> 5;

    for (int i = tid; i < 9 * 32 * 32; i += 256) Wlds[i] = W[i];
    __syncthreads();

    const int dbase = blockIdx.x * 64;
    for (int it = 0; it < 8; ++it) {
        const int m = dbase + it * 8 + slot;
        const bool valid = (m < M_REAL);

        float t[9];
#pragma unroll
        for (int b = 0; b < 9; ++b) t[b] = 0.0f;

        const int deg = valid ? min(counts[m], maxdeg) : 0;
        const uint4* bd4 =
            reinterpret_cast<const uint4*>(bucketData + (size_t)m * maxdeg);

        for (int i = 0; i < deg; i += 4) {
            // slots i..i+3 (maxdeg%4==0 so never crosses this dst's bucket)
            const uint4 q0 = bd4[i >> 1];
            const uint4 q1 = bd4[(i >> 1) + 1];
            const unsigned pr[4] = {q0.x, q0.z, q1.x, q1.z};
            const unsigned pd[4] = {q0.y, q0.w, q1.y, q1.w};

            float x[4];
#pragma unroll
            for (int j = 0; j < 4; ++j) {
                const unsigned rr =
                    use_hi ? (pr[j] >> 16) : (pr[j] & 0xffffu);
                const float xv = xin[(size_t)rr * 32 + lane];
                x[j] = (i + j < deg) ? xv : 0.0f;   // tail mask
            }
#pragma unroll
            for (int j = 0; j < 4; ++j) {
                __half2 h2 = *reinterpret_cast<const __half2*>(&pd[j]);
                const float du = __low2float(h2);
                const float dv = __high2float(h2);
                const float u0 = __expf(-(du + 1.f) * (du + 1.f));
                const float u1 = __expf(-du * du);
                const float u2 = __expf(-(du - 1.f) * (du - 1.f));
                const float w0 = __expf(-(dv + 1.f) * (dv + 1.f));
                const float w1 = __expf(-dv * dv);
                const float w2 = __expf(-(dv - 1.f) * (dv - 1.f));
                const float xv = x[j];
                const float v0 = w0 * xv, v1 = w1 * xv, v2 = w2 * xv;
                t[0] += u0 * v0; t[1] += u0 * v1; t[2] += u0 * v2;
                t[3] += u1 * v0; t[4] += u1 * v1; t[5] += u1 * v2;
                t[6] += u2 * v0; t[7] += u2 * v1; t[8] += u2 * v2;
            }
        }

        // exchange t across lanes: t_lds[slot][k][b]
        {
            float* tl = &t_lds[(slot * 32 + lane) * 12];
#pragma unroll
            for (int b = 0; b < 9; ++b) tl[b] = t[b];
        }
        __syncthreads();

        if (valid) {
            float acc = 0.0f;
            const float4* tb4 =
                reinterpret_cast<const float4*>(&t_lds[slot * 32 * 12]);
            const float* wl = &Wlds[lane];
#pragma unroll 4
            for (int k = 0; k < 32; ++k) {
                const float4 a0 = tb4[k * 3];
                const float4 a1 = tb4[k * 3 + 1];
                const float4 a2 = tb4[k * 3 + 2];
                const float* wk = wl + k * 32;
                acc += a0.x * wk[0]    + a0.y * wk[1024] + a0.z * wk[2048]
                     + a0.w * wk[3072] + a1.x * wk[4096] + a1.y * wk[5120]
                     + a1.z * wk[6144] + a1.w * wk[7168] + a2.x * wk[8192];
            }
            if (act) acc = fmaxf(acc, 0.0f);
            yout[m * 32 + lane] = acc;
        }
        __syncthreads();
    }
}

// ---------------------------------------------------------------------------
// Fill ghost rows of the final output: out[M+i] = out[ghost[M+i]]
// ---------------------------------------------------------------------------
__global__ void ghost_kernel(const int* __restrict__ ghost,
                             float* __restrict__ out) {
    int idx = blockIdx.x * blockDim.x + threadIdx.x;
    if (idx >= (N_TOT - M_REAL) * 32) return;
    int i = idx >> 5;
    int k = idx & 31;
    int g = ghost[M_REAL + i];
    out[(M_REAL + i) * 32 + k] = out[g * 32 + k];
}

extern "C" void kernel_launch(void* const* d_in, const int* in_sizes, int n_in,
                              void* d_out, int out_size, void* d_ws, size_t ws_size,
                              hipStream_t stream) {
    const float* positions = (const float*)d_in[0];
    const float* features  = (const float*)d_in[1];
    const float* outpos    = (const float*)d_in[2];
    const int*   ghost     = (const int*)d_in[3];
    const float* support   = (const float*)d_in[4];
    const int*   edge      = (const int*)d_in[5];   // [2,E]
    const float* W0        = (const float*)d_in[6];
    const float* W1        = (const float*)d_in[7];
    const float* W2        = (const float*)d_in[8];
    float* out = (float*)d_out;

    // workspace layout: counts | bucketData | out0 | out1
    const size_t countsB = ((size_t)M_REAL * 4 + 255) / 256 * 256;
    const size_t outB    = (size_t)M_REAL * 32 * 4;
    // pick bucket depth that fits ws (max observed degree ~40 for Poisson(18.5))
    const size_t need64 = countsB + (size_t)M_REAL * 64 * 8 + 2 * outB;
    const int maxdeg = (ws_size >= need64) ? 64 : 48;

    char* ws = (char*)d_ws;
    int*   counts     = (int*)ws;                 ws += countsB;
    uint2* bucketData = (uint2*)ws;               ws += (size_t)M_REAL * maxdeg * 8;
    float* out0       = (float*)ws;               ws += outB;
    float* out1       = (float*)ws;

    const int* erow = edge;
    const int* ecol = edge + N_EDGE;

    hipMemsetAsync(counts, 0, (size_t)M_REAL * 4, stream);
    hipMemsetAsync(bucketData, 0, (size_t)M_REAL * maxdeg * 8, stream);
    build_kernel<<<(N_EDGE + 255) / 256, 256, 0, stream>>>(
        erow, ecol, ghost, positions, outpos, support, counts, bucketData, maxdeg);

    dim3 grid((M_REAL + 63) / 64), block(256);
    // layer 0: features has all N_TOT rows -> use raw row (lo16), relu
    conv_kernel<<<grid, block, 0, stream>>>(features, counts, bucketData, W0,
                                            out0, 1, 0, maxdeg);
    // layer 1: gather from out0 via remapped row (hi16), relu
    conv_kernel<<<grid, block, 0, stream>>>(out0, counts, bucketData, W1,
                                            out1, 1, 1, maxdeg);
    // layer 2: no act, write real rows of d_out
    conv_kernel<<<grid, block, 0, stream>>>(out1, counts, bucketData, W2,
                                            out, 0, 1, maxdeg);
    ghost_kernel<<<((N_TOT - M_REAL) * 32 + 255) / 256, 256, 0, stream>>>(ghost, out);
}

// Round 4
// 480.475 us; speedup vs baseline: 2.5305x; 1.0274x over previous
//
#include <hip/hip_runtime.h>
#include <hip/hip_fp16.h>

#define M_REAL   54000
#define N_TOT    60000
#define N_EDGE   1000000

// ---------------------------------------------------------------------------
// Build: per edge, precompute EVERYTHING a conv layer needs, packed to 16 B:
//   .x = raw_row | remap_row<<16   (both < 65536)
//   .y = half2(u0,u1)  .z = half2(u2,v0)  .w = half2(v1,v2)
// where u_i = exp(-(du-c_i)^2), v_j = exp(-(dv-c_j)^2), c = {-1,0,1}.
// Basis is layer-invariant, so this runs once; conv layers do only FMAs.
// ---------------------------------------------------------------------------
__global__ void build_kernel(const int* __restrict__ row,
                             const int* __restrict__ col,
                             const int* __restrict__ ghost,
                             const float* __restrict__ positions,
                             const float* __restrict__ outpos,
                             const float* __restrict__ supportp,
                             int* __restrict__ counts,
                             uint4* __restrict__ bucketData,
                             int maxdeg) {
    int e = blockIdx.x * blockDim.x + threadIdx.x;
    if (e >= N_EDGE) return;
    const int c = col[e];
    const int r = row[e];
    const int rm = (r < M_REAL) ? r : ghost[r];
    const float invs = 1.0f / supportp[0];
    float du = (outpos[2 * c]     - positions[2 * r])     * invs;
    float dv = (outpos[2 * c + 1] - positions[2 * r + 1]) * invs;
    du = fminf(fmaxf(du, -1.0f), 1.0f);
    dv = fminf(fmaxf(dv, -1.0f), 1.0f);
    const float u0 = __expf(-(du + 1.f) * (du + 1.f));
    const float u1 = __expf(-du * du);
    const float u2 = __expf(-(du - 1.f) * (du - 1.f));
    const float v0 = __expf(-(dv + 1.f) * (dv + 1.f));
    const float v1 = __expf(-dv * dv);
    const float v2 = __expf(-(dv - 1.f) * (dv - 1.f));
    __half2 h01 = __floats2half2_rn(u0, u1);
    __half2 h20 = __floats2half2_rn(u2, v0);
    __half2 h12 = __floats2half2_rn(v1, v2);
    uint4 d;
    d.x = (unsigned)r | ((unsigned)rm << 16);
    d.y = *reinterpret_cast<unsigned*>(&h01);
    d.z = *reinterpret_cast<unsigned*>(&h20);
    d.w = *reinterpret_cast<unsigned*>(&h12);
    int p = atomicAdd(&counts[c], 1);
    if (p < maxdeg) bucketData[(size_t)c * maxdeg + p] = d;
}

// ---------------------------------------------------------------------------
// Pad each bucket to a multiple of 4 with zero entries (zero halves => zero
// contribution, row 0 gather is safe) and store the ROUNDED count, so the
// conv edge loop needs no tail masking at all.
// ---------------------------------------------------------------------------
__global__ void pad_kernel(int* __restrict__ counts,
                           uint4* __restrict__ bucketData,
                           int maxdeg) {
    int m = blockIdx.x * blockDim.x + threadIdx.x;
    if (m >= M_REAL) return;
    int deg = counts[m];
    if (deg > maxdeg) deg = maxdeg;
    int deg4 = (deg + 3) & ~3;
    uint4 z = {0u, 0u, 0u, 0u};
    for (int p = deg; p < deg4; ++p)
        bucketData[(size_t)m * maxdeg + p] = z;
    counts[m] = deg4;
}

// ---------------------------------------------------------------------------
// Fused conv layer. Block = 256 = 8 half-waves; half-wave owns one dst per
// iteration (8 its -> 64 dsts/block). Lane = input feat k (edge phase) then
// output feat l (einsum). Edge loop: 4 edges/group, 4 independent gathers in
// flight, zero per-edge transcendentals.
// ---------------------------------------------------------------------------
__global__ __launch_bounds__(256) void conv_kernel(
        const float* __restrict__ xin,        // [*,32]
        const int*   __restrict__ counts,     // [M] (rounded to x4)
        const uint4* __restrict__ bucketData, // [M*maxdeg]
        const float* __restrict__ W,          // [9,32,32] (b,k,l)
        float*       __restrict__ yout,       // [M,32]
        int act, int use_hi, int maxdeg) {
    __shared__ float Wlds[9 * 32 * 32];        // 36 KB
    __shared__ float t_lds[8 * 32 * 12];       // 12 KB (pad 9 -> 12 for float4)

    const int tid  = threadIdx.x;
    const int lane = tid & 31;
    const int slot = tid >> 5;

    for (int i = tid; i < 9 * 32 * 32; i += 256) Wlds[i] = W[i];
    __syncthreads();

    const int dbase = blockIdx.x * 64;
    for (int it = 0; it < 8; ++it) {
        const int m = dbase + it * 8 + slot;
        const bool valid = (m < M_REAL);

        float t[9];
#pragma unroll
        for (int b = 0; b < 9; ++b) t[b] = 0.0f;

        const int deg4 = valid ? counts[m] : 0;
        const uint4* bd = bucketData + (size_t)m * maxdeg;

        for (int i = 0; i < deg4; i += 4) {
            uint4 q[4];
#pragma unroll
            for (int j = 0; j < 4; ++j) q[j] = bd[i + j];

            float x[4];
#pragma unroll
            for (int j = 0; j < 4; ++j) {
                const unsigned rr =
                    use_hi ? (q[j].x >> 16) : (q[j].x & 0xffffu);
                x[j] = xin[(size_t)rr * 32 + lane];
            }
#pragma unroll
            for (int j = 0; j < 4; ++j) {
                const float2 U01 =
                    __half22float2(*reinterpret_cast<const __half2*>(&q[j].y));
                const float2 U2V0 =
                    __half22float2(*reinterpret_cast<const __half2*>(&q[j].z));
                const float2 V12 =
                    __half22float2(*reinterpret_cast<const __half2*>(&q[j].w));
                const float xv = x[j];
                const float vx0 = U2V0.y * xv;   // v0*x
                const float vx1 = V12.x * xv;    // v1*x
                const float vx2 = V12.y * xv;    // v2*x
                t[0] += U01.x * vx0; t[1] += U01.x * vx1; t[2] += U01.x * vx2;
                t[3] += U01.y * vx0; t[4] += U01.y * vx1; t[5] += U01.y * vx2;
                t[6] += U2V0.x * vx0; t[7] += U2V0.x * vx1; t[8] += U2V0.x * vx2;
            }
        }

        // exchange t across lanes: t_lds[slot][k][b]
        {
            float* tl = &t_lds[(slot * 32 + lane) * 12];
#pragma unroll
            for (int b = 0; b < 9; ++b) tl[b] = t[b];
        }
        __syncthreads();

        if (valid) {
            float acc = 0.0f;
            const float4* tb4 =
                reinterpret_cast<const float4*>(&t_lds[slot * 32 * 12]);
            const float* wl = &Wlds[lane];
#pragma unroll 4
            for (int k = 0; k < 32; ++k) {
                const float4 a0 = tb4[k * 3];
                const float4 a1 = tb4[k * 3 + 1];
                const float4 a2 = tb4[k * 3 + 2];
                const float* wk = wl + k * 32;
                acc += a0.x * wk[0]    + a0.y * wk[1024] + a0.z * wk[2048]
                     + a0.w * wk[3072] + a1.x * wk[4096] + a1.y * wk[5120]
                     + a1.z * wk[6144] + a1.w * wk[7168] + a2.x * wk[8192];
            }
            if (act) acc = fmaxf(acc, 0.0f);
            yout[m * 32 + lane] = acc;
        }
        __syncthreads();
    }
}

// ---------------------------------------------------------------------------
// Fill ghost rows of the final output: out[M+i] = out[ghost[M+i]]
// ---------------------------------------------------------------------------
__global__ void ghost_kernel(const int* __restrict__ ghost,
                             float* __restrict__ out) {
    int idx = blockIdx.x * blockDim.x + threadIdx.x;
    if (idx >= (N_TOT - M_REAL) * 32) return;
    int i = idx >> 5;
    int k = idx & 31;
    int g = ghost[M_REAL + i];
    out[(M_REAL + i) * 32 + k] = out[g * 32 + k];
}

extern "C" void kernel_launch(void* const* d_in, const int* in_sizes, int n_in,
                              void* d_out, int out_size, void* d_ws, size_t ws_size,
                              hipStream_t stream) {
    const float* positions = (const float*)d_in[0];
    const float* features  = (const float*)d_in[1];
    const float* outpos    = (const float*)d_in[2];
    const int*   ghost     = (const int*)d_in[3];
    const float* support   = (const float*)d_in[4];
    const int*   edge      = (const int*)d_in[5];   // [2,E]
    const float* W0        = (const float*)d_in[6];
    const float* W1        = (const float*)d_in[7];
    const float* W2        = (const float*)d_in[8];
    float* out = (float*)d_out;

    // ws layout: counts | bucketData(16B entries) | out1.
    // out0 lives in d_out's real-row region (overwritten by layer 2 later).
    const size_t countsB = ((size_t)M_REAL * 4 + 255) / 256 * 256;
    const size_t outB    = (size_t)M_REAL * 32 * 4;
    const size_t need64  = countsB + (size_t)M_REAL * 64 * 16 + outB;
    const int maxdeg = (ws_size >= need64) ? 64 : 48;

    char* ws = (char*)d_ws;
    int*   counts     = (int*)ws;    ws += countsB;
    uint4* bucketData = (uint4*)ws;  ws += (size_t)M_REAL * maxdeg * 16;
    float* out1       = (float*)ws;
    float* out0       = out;         // reuse d_out real-row region as scratch

    const int* erow = edge;
    const int* ecol = edge + N_EDGE;

    hipMemsetAsync(counts, 0, (size_t)M_REAL * 4, stream);
    build_kernel<<<(N_EDGE + 255) / 256, 256, 0, stream>>>(
        erow, ecol, ghost, positions, outpos, support, counts, bucketData, maxdeg);
    pad_kernel<<<(M_REAL + 255) / 256, 256, 0, stream>>>(counts, bucketData, maxdeg);

    dim3 grid((M_REAL + 63) / 64), block(256);
    // layer 0: features has all N_TOT rows -> raw row (lo16), relu
    conv_kernel<<<grid, block, 0, stream>>>(features, counts, bucketData, W0,
                                            out0, 1, 0, maxdeg);
    // layer 1: gather from out0 via remapped row (hi16), relu
    conv_kernel<<<grid, block, 0, stream>>>(out0, counts, bucketData, W1,
                                            out1, 1, 1, maxdeg);
    // layer 2: no act, write real rows of d_out
    conv_kernel<<<grid, block, 0, stream>>>(out1, counts, bucketData, W2,
                                            out, 0, 1, maxdeg);
    ghost_kernel<<<((N_TOT - M_REAL) * 32 + 255) / 256, 256, 0, stream>>>(ghost, out);
}

// Round 5
// 193.599 us; speedup vs baseline: 6.2803x; 2.4818x over previous
//
#include <hip/hip_runtime.h>
#include <hip/hip_fp16.h>
#include <hip/hip_bf16.h>

#define M_REAL   54000
#define N_TOT    60000
#define N_EDGE   1000000

typedef __attribute__((ext_vector_type(8)))  short short8;
typedef __attribute__((ext_vector_type(16))) float f32x16;

// ---------------------------------------------------------------------------
// Build: per edge, precompute everything, packed to 16 B per bucket slot:
//   .x = raw_row | remap_row<<16
//   .y = half2(u0,u1)  .z = half2(u2,v0)  .w = half2(v1,v2)
// ---------------------------------------------------------------------------
__global__ void build_kernel(const int* __restrict__ row,
                             const int* __restrict__ col,
                             const int* __restrict__ ghost,
                             const float* __restrict__ positions,
                             const float* __restrict__ outpos,
                             const float* __restrict__ supportp,
                             int* __restrict__ counts,
                             uint4* __restrict__ bucketData,
                             int maxdeg) {
    int e = blockIdx.x * blockDim.x + threadIdx.x;
    if (e >= N_EDGE) return;
    const int c = col[e];
    const int r = row[e];
    const int rm = (r < M_REAL) ? r : ghost[r];
    const float invs = 1.0f / supportp[0];
    float du = (outpos[2 * c]     - positions[2 * r])     * invs;
    float dv = (outpos[2 * c + 1] - positions[2 * r + 1]) * invs;
    du = fminf(fmaxf(du, -1.0f), 1.0f);
    dv = fminf(fmaxf(dv, -1.0f), 1.0f);
    const float u0 = __expf(-(du + 1.f) * (du + 1.f));
    const float u1 = __expf(-du * du);
    const float u2 = __expf(-(du - 1.f) * (du - 1.f));
    const float v0 = __expf(-(dv + 1.f) * (dv + 1.f));
    const float v1 = __expf(-dv * dv);
    const float v2 = __expf(-(dv - 1.f) * (dv - 1.f));
    __half2 h01 = __floats2half2_rn(u0, u1);
    __half2 h20 = __floats2half2_rn(u2, v0);
    __half2 h12 = __floats2half2_rn(v1, v2);
    uint4 d;
    d.x = (unsigned)r | ((unsigned)rm << 16);
    d.y = *reinterpret_cast<unsigned*>(&h01);
    d.z = *reinterpret_cast<unsigned*>(&h20);
    d.w = *reinterpret_cast<unsigned*>(&h12);
    int p = atomicAdd(&counts[c], 1);
    if (p < maxdeg) bucketData[(size_t)c * maxdeg + p] = d;
}

// Pad buckets to x4 with zero entries; store rounded count.
__global__ void pad_kernel(int* __restrict__ counts,
                           uint4* __restrict__ bucketData,
                           int maxdeg) {
    int m = blockIdx.x * blockDim.x + threadIdx.x;
    if (m >= M_REAL) return;
    int deg = counts[m];
    if (deg > maxdeg) deg = maxdeg;
    int deg4 = (deg + 3) & ~3;
    uint4 z = {0u, 0u, 0u, 0u};
    for (int p = deg; p < deg4; ++p)
        bucketData[(size_t)m * maxdeg + p] = z;
    counts[m] = deg4;
}

// Convert W0,W1,W2 (f32 [288,32] each) to bf16 Wb[3][288*32].
__global__ void wprep_kernel(const float* __restrict__ W0,
                             const float* __restrict__ W1,
                             const float* __restrict__ W2,
                             unsigned short* __restrict__ Wb) {
    int i = blockIdx.x * blockDim.x + threadIdx.x;
    if (i >= 3 * 9216) return;
    const float* src = (i < 9216) ? W0 : (i < 2 * 9216 ? W1 : W2);
    __hip_bfloat16 b = __float2bfloat16(src[i % 9216]);
    Wb[i] = __builtin_bit_cast(unsigned short, b);
}

// ---------------------------------------------------------------------------
// Edge phase: one dst per half-wave, NO LDS, no block-level sync. Grid is
// exactly M/8 blocks. Accumulates t[9] in registers, stores T[m,288] bf16
// with kk = b*32+lane (so T x W is a plain GEMM, W already [288,32]).
// ---------------------------------------------------------------------------
__global__ __launch_bounds__(256) void edge_kernel(
        const float* __restrict__ xin,        // [*,32]
        const int*   __restrict__ counts,     // [M] (x4-rounded)
        const uint4* __restrict__ bucketData, // [M*maxdeg]
        unsigned short* __restrict__ Tb,      // [M,288] bf16
        int use_hi, int maxdeg) {
    const int lane = threadIdx.x & 31;
    const int slot = threadIdx.x >> 5;
    const int m = blockIdx.x * 8 + slot;      // grid exact: M_REAL/8

    float t[9];
#pragma unroll
    for (int b = 0; b < 9; ++b) t[b] = 0.0f;

    const int deg4 = counts[m];
    const uint4* bd = bucketData + (size_t)m * maxdeg;

    for (int i = 0; i < deg4; i += 4) {
        uint4 q[4];
#pragma unroll
        for (int j = 0; j < 4; ++j) q[j] = bd[i + j];
        float x[4];
#pragma unroll
        for (int j = 0; j < 4; ++j) {
            const unsigned rr = use_hi ? (q[j].x >> 16) : (q[j].x & 0xffffu);
            x[j] = xin[(size_t)rr * 32 + lane];
        }
#pragma unroll
        for (int j = 0; j < 4; ++j) {
            const float2 U01  = __half22float2(*reinterpret_cast<const __half2*>(&q[j].y));
            const float2 U2V0 = __half22float2(*reinterpret_cast<const __half2*>(&q[j].z));
            const float2 V12  = __half22float2(*reinterpret_cast<const __half2*>(&q[j].w));
            const float xv = x[j];
            const float vx0 = U2V0.y * xv;
            const float vx1 = V12.x * xv;
            const float vx2 = V12.y * xv;
            t[0] += U01.x * vx0;  t[1] += U01.x * vx1;  t[2] += U01.x * vx2;
            t[3] += U01.y * vx0;  t[4] += U01.y * vx1;  t[5] += U01.y * vx2;
            t[6] += U2V0.x * vx0; t[7] += U2V0.x * vx1; t[8] += U2V0.x * vx2;
        }
    }

    unsigned short* tr = Tb + (size_t)m * 288 + lane;
#pragma unroll
    for (int b = 0; b < 9; ++b) {
        __hip_bfloat16 h = __float2bfloat16(t[b]);
        tr[b * 32] = __builtin_bit_cast(unsigned short, h);
    }
}

// ---------------------------------------------------------------------------
// GEMM: out[M,32] = T[M,288](bf16) x W[288,32](bf16), f32 accum, optional relu.
// mfma_f32_32x32x16_bf16. Block = 256 thr = 4 waves; wave owns 64 rows
// (2 x 32-row subtiles, interleaved acc chains). 18 K-steps.
// A frag: row = lane&31, k = (lane>>5)*8 + j.  B frag: col = lane&31, same k.
// C/D: col = lane&31, row = (reg&3) + 8*(reg>>2) + 4*(lane>>5).
// ---------------------------------------------------------------------------
__global__ __launch_bounds__(256) void gemm_kernel(
        const unsigned short* __restrict__ Tb,  // [M,288] bf16
        const unsigned short* __restrict__ Wb,  // [288,32] bf16
        float* __restrict__ yout,               // [M,32]
        int act) {
    const int wave = threadIdx.x >> 6;
    const int lane = threadIdx.x & 63;
    const int col  = lane & 31;
    const int kh   = lane >> 5;                 // 0/1
    const int m0   = blockIdx.x * 256 + wave * 64;

    // Preload all 18 B fragments into registers (static indexing only).
    short8 bfr[18];
#pragma unroll
    for (int s = 0; s < 18; ++s) {
        union { unsigned short u[8]; short8 v; } tmp;
#pragma unroll
        for (int j = 0; j < 8; ++j)
            tmp.u[j] = Wb[(s * 16 + kh * 8 + j) * 32 + col];
        bfr[s] = tmp.v;
    }

    const int r0 = m0 + (lane & 31);
    const int r1 = r0 + 32;
    const int r0c = (r0 < M_REAL) ? r0 : (M_REAL - 1);
    const int r1c = (r1 < M_REAL) ? r1 : (M_REAL - 1);
    const uint4* a0 = reinterpret_cast<const uint4*>(Tb + (size_t)r0c * 288) + kh;
    const uint4* a1 = reinterpret_cast<const uint4*>(Tb + (size_t)r1c * 288) + kh;

    f32x16 acc0 = {};
    f32x16 acc1 = {};
#pragma unroll
    for (int s = 0; s < 18; ++s) {
        union { uint4 u; short8 v; } av0, av1;
        av0.u = a0[s * 2];
        av1.u = a1[s * 2];
        acc0 = __builtin_amdgcn_mfma_f32_32x32x16_bf16(av0.v, bfr[s], acc0, 0, 0, 0);
        acc1 = __builtin_amdgcn_mfma_f32_32x32x16_bf16(av1.v, bfr[s], acc1, 0, 0, 0);
    }

#pragma unroll
    for (int r = 0; r < 16; ++r) {
        const int rr  = (r & 3) + 8 * (r >> 2) + 4 * kh;
        const int om0 = m0 + rr;
        const int om1 = m0 + 32 + rr;
        float v0 = acc0[r], v1 = acc1[r];
        if (act) { v0 = fmaxf(v0, 0.0f); v1 = fmaxf(v1, 0.0f); }
        if (om0 < M_REAL) yout[om0 * 32 + col] = v0;
        if (om1 < M_REAL) yout[om1 * 32 + col] = v1;
    }
}

// Fill ghost rows of the final output: out[M+i] = out[ghost[M+i]]
__global__ void ghost_kernel(const int* __restrict__ ghost,
                             float* __restrict__ out) {
    int idx = blockIdx.x * blockDim.x + threadIdx.x;
    if (idx >= (N_TOT - M_REAL) * 32) return;
    int i = idx >> 5;
    int k = idx & 31;
    int g = ghost[M_REAL + i];
    out[(M_REAL + i) * 32 + k] = out[g * 32 + k];
}

extern "C" void kernel_launch(void* const* d_in, const int* in_sizes, int n_in,
                              void* d_out, int out_size, void* d_ws, size_t ws_size,
                              hipStream_t stream) {
    const float* positions = (const float*)d_in[0];
    const float* features  = (const float*)d_in[1];
    const float* outpos    = (const float*)d_in[2];
    const int*   ghost     = (const int*)d_in[3];
    const float* support   = (const float*)d_in[4];
    const int*   edge      = (const int*)d_in[5];   // [2,E]
    const float* W0        = (const float*)d_in[6];
    const float* W1        = (const float*)d_in[7];
    const float* W2        = (const float*)d_in[8];
    float* out = (float*)d_out;

    auto al = [](size_t x) { return (x + 255) & ~(size_t)255; };
    const size_t countsB = al((size_t)M_REAL * 4);
    const size_t TbB     = al((size_t)M_REAL * 288 * 2);
    const size_t WbB     = al((size_t)3 * 9216 * 2);
    const size_t outB    = al((size_t)M_REAL * 32 * 4);
    const size_t need64  = countsB + (size_t)M_REAL * 64 * 16 + TbB + WbB + outB;
    const int maxdeg = (ws_size >= need64) ? 64 : 48;

    char* ws = (char*)d_ws;
    int*            counts     = (int*)ws;            ws += countsB;
    uint4*          bucketData = (uint4*)ws;          ws += (size_t)M_REAL * maxdeg * 16;
    unsigned short* Tb         = (unsigned short*)ws; ws += TbB;
    unsigned short* Wb         = (unsigned short*)ws; ws += WbB;
    float*          out1       = (float*)ws;
    float*          out0       = out;   // reuse d_out real-row region as scratch

    const int* erow = edge;
    const int* ecol = edge + N_EDGE;

    hipMemsetAsync(counts, 0, (size_t)M_REAL * 4, stream);
    build_kernel<<<(N_EDGE + 255) / 256, 256, 0, stream>>>(
        erow, ecol, ghost, positions, outpos, support, counts, bucketData, maxdeg);
    pad_kernel<<<(M_REAL + 255) / 256, 256, 0, stream>>>(counts, bucketData, maxdeg);
    wprep_kernel<<<(3 * 9216 + 255) / 256, 256, 0, stream>>>(W0, W1, W2, Wb);

    const int egrid = M_REAL / 8;                 // 6750, exact
    const int ggrid = (M_REAL + 255) / 256;       // 211

    // layer 0: gather raw rows (lo16) from features
    edge_kernel<<<egrid, 256, 0, stream>>>(features, counts, bucketData, Tb, 0, maxdeg);
    gemm_kernel<<<ggrid, 256, 0, stream>>>(Tb, Wb, out0, 1);
    // layer 1: gather remapped rows (hi16) from out0
    edge_kernel<<<egrid, 256, 0, stream>>>(out0, counts, bucketData, Tb, 1, maxdeg);
    gemm_kernel<<<ggrid, 256, 0, stream>>>(Tb, Wb + 9216, out1, 1);
    // layer 2: no act, write real rows of d_out
    edge_kernel<<<egrid, 256, 0, stream>>>(out1, counts, bucketData, Tb, 1, maxdeg);
    gemm_kernel<<<ggrid, 256, 0, stream>>>(Tb, Wb + 2 * 9216, out, 0);

    ghost_kernel<<<((N_TOT - M_REAL) * 32 + 255) / 256, 256, 0, stream>>>(ghost, out);
}